// Round 12
// baseline (1526.081 us; speedup 1.0000x reference)
//
#include <hip/hip_runtime.h>
#include <hip/hip_bf16.h>
#include <hip/hip_fp16.h>

#define NN 50000
#define EE 800000
#define GG 128
#define HH 128
#define XPB 136   // fp16 LDS pitch: 272B rows
#define M2P 130   // fp32 msg2 pitch

typedef __bf16 bf16;
typedef __attribute__((ext_vector_type(8))) __bf16 bf16x8;
typedef __attribute__((ext_vector_type(4))) float f32x4;
typedef __attribute__((ext_vector_type(4))) unsigned int u32x4;

__device__ __forceinline__ float silu_f(float x) { return x / (1.0f + __expf(-x)); }

// ---------------------------------------------------------------- weights prep
__global__ void prep_weights(const float* __restrict__ w1, const float* __restrict__ w2,
                             const float* __restrict__ u1, const float* __restrict__ u2,
                             const float* __restrict__ ee, const float* __restrict__ mb1,
                             bf16* __restrict__ W1abt, bf16* __restrict__ W1rt,
                             bf16* __restrict__ W2t, bf16* __restrict__ U1t,
                             bf16* __restrict__ U2t) {
    int idx = blockIdx.x * 256 + threadIdx.x;
    if (idx < 131072) {                        // W1abt: 4*256*128
        int l = idx >> 15, rem = idx & 32767;
        int c = rem >> 7, k = rem & 127;
        int krow = k + ((c >= 128) ? 128 : 0);
        W1abt[idx] = (bf16)w1[(size_t)l * 417 * 128 + (size_t)krow * 128 + (c & 127)];
    } else if ((idx -= 131072) < 32768) {      // W1rt: 4*128*64
        int l = idx >> 13, rem = idx & 8191;
        int c = rem >> 6, k = rem & 63;
        const float* w1l = w1 + (size_t)l * 417 * 128;
        float v = 0.0f;
        if (k < 32) v = w1l[(size_t)(384 + k) * 128 + c];
        else if (k == 32) v = w1l[(size_t)416 * 128 + c];
        else if (k == 33) {
            v = mb1[l * 128 + c];
            for (int t = 0; t < 128; ++t)
                v += ee[(size_t)l * 256 + t] * w1l[(size_t)(256 + t) * 128 + c];
        } else if (k == 34) {
            for (int t = 0; t < 128; ++t)
                v += (ee[(size_t)l * 256 + 128 + t] - ee[(size_t)l * 256 + t]) *
                     w1l[(size_t)(256 + t) * 128 + c];
        }
        W1rt[idx] = (bf16)v;
    } else if ((idx -= 32768) < 65536) {       // W2t
        int l = idx / 16384, rem = idx % 16384;
        int n = rem / 128, k = rem % 128;
        W2t[idx] = (bf16)w2[(size_t)l * 16384 + (size_t)k * 128 + n];
    } else if ((idx -= 65536) < 131072) {      // U1t ; u1 is [4][256][128]
        int l = idx / 32768, rem = idx % 32768;
        int n = rem / 256, k = rem % 256;
        U1t[idx] = (bf16)u1[(size_t)l * 32768 + (size_t)k * 128 + n];
    } else if ((idx -= 131072) < 65536) {      // U2t ; u2 is [4][128][128]
        int l = idx / 16384, rem = idx % 16384;
        int n = rem / 128, k = rem % 128;
        U2t[idx] = (bf16)u2[(size_t)l * 16384 + (size_t)k * 128 + n];
    }
}

// ---------------------------------------------------------------- time MLP
__global__ void time_mlp(const float* __restrict__ t, const float* __restrict__ w1,
                         const float* __restrict__ b1, const float* __restrict__ w2,
                         const float* __restrict__ b2, float* __restrict__ tf) {
    int g = blockIdx.x, c = threadIdx.x;  // 128 threads
    __shared__ float sL[64], uT[128];
    float tv = t[g];
    if (c < 32) {
        float fr = expf(-(float)c * (logf(10000.0f) / 31.0f));
        float arg = tv * fr;
        sL[c] = sinf(arg);
        sL[c + 32] = cosf(arg);
    }
    __syncthreads();
    float acc = b1[c];
    for (int k = 0; k < 64; ++k) acc += sL[k] * w1[k * 128 + c];
    uT[c] = silu_f(acc);
    __syncthreads();
    float acc2 = b2[c];
    for (int k = 0; k < 128; ++k) acc2 += uT[k] * w2[k * 128 + c];
    tf[g * 128 + c] = acc2;
}

// ---------------------------------------------------------------- edge preprocess
__global__ void edge_pre(const int* __restrict__ ei, const float* __restrict__ pos,
                         float* __restrict__ dist_raw, int* __restrict__ cnt) {
    int e = blockIdx.x * 256 + threadIdx.x;
    if (e >= EE) return;
    int s = ei[e], d = ei[EE + e];
    float dx = pos[s * 3 + 0] - pos[d * 3 + 0];
    float dy = pos[s * 3 + 1] - pos[d * 3 + 1];
    float dz = pos[s * 3 + 2] - pos[d * 3 + 2];
    dist_raw[e] = sqrtf(dx * dx + dy * dy + dz * dz);
    atomicAdd(&cnt[d], 1);
}

__global__ void scan_kernel(const int* __restrict__ cnt, int* __restrict__ cursor) {
    __shared__ int part[1024];
    int t = threadIdx.x;
    const int per = (NN + 1023) / 1024;
    int start = t * per, end = min(start + per, NN);
    int s = 0;
    for (int i = start; i < end; ++i) s += cnt[i];
    part[t] = s;
    __syncthreads();
    for (int off = 1; off < 1024; off <<= 1) {
        int v = (t >= off) ? part[t - off] : 0;
        __syncthreads();
        part[t] += v;
        __syncthreads();
    }
    int base = (t == 0) ? 0 : part[t - 1];
    for (int i = start; i < end; ++i) { cursor[i] = base; base += cnt[i]; }
}

// packs src (16b) | type (bit 16) into su_s
__global__ void scatter_kernel(const int* __restrict__ ei, const int* __restrict__ et,
                               const float* __restrict__ dist_raw, int* __restrict__ cursor,
                               int* __restrict__ su_s, int* __restrict__ dst_s,
                               float* __restrict__ dist_s) {
    int e = blockIdx.x * 256 + threadIdx.x;
    if (e >= EE) return;
    int d = ei[EE + e];
    int p = atomicAdd(&cursor[d], 1);
    su_s[p] = ei[e] | (et[e] << 16);
    dst_s[p] = d;
    dist_s[p] = dist_raw[e];
}

// ---------------------------------------------------------------- node init + LN + X-GEMM (fused)
__global__ __launch_bounds__(256) void node_init_fused(
    const int* __restrict__ z, const int* __restrict__ nt, const int* __restrict__ batch,
    const float* __restrict__ tf, const float* __restrict__ emb_z,
    const float* __restrict__ emb_nt, const float* __restrict__ g,
    const float* __restrict__ b, float* __restrict__ hg, bf16* __restrict__ hb,
    const bf16* __restrict__ W1abt, __half* __restrict__ Xsh, __half* __restrict__ Xdh) {
    __shared__ bf16 hnL[64 * 128];   // swizzled chunks
    const int tid = threadIdx.x;
    const int lane = tid & 63, wave = tid >> 6;
    const int wr = wave >> 1, wc = wave & 1;
    const int lrow = lane & 15, lgrp = lane >> 4;
    const int nb0 = blockIdx.x * 64;
    const int r0 = wr * 32 + lrow, r1 = r0 + 16;

    // phase 1: build h, LN, write out, stage into hnL
    {
        const int row = tid >> 2, sl = tid & 3;
        const int node = nb0 + row;
        const bool ok = node < NN;
        const int c0 = sl * 32;
        float v[32];
        if (ok) {
            const int zz = min(max(z[node], 0), 127);
            const float* ez = emb_z + (size_t)zz * 128 + c0;
            const float* en = emb_nt + (size_t)nt[node] * 128 + c0;
            const float* tp = tf + (size_t)batch[node] * 128 + c0;
#pragma unroll
            for (int k = 0; k < 8; ++k) {
                const float4 a = *(const float4*)(ez + k * 4);
                const float4 c_ = *(const float4*)(en + k * 4);
                const float4 d_ = *(const float4*)(tp + k * 4);
                v[k * 4 + 0] = a.x + c_.x + d_.x;
                v[k * 4 + 1] = a.y + c_.y + d_.y;
                v[k * 4 + 2] = a.z + c_.z + d_.z;
                v[k * 4 + 3] = a.w + c_.w + d_.w;
            }
        } else {
#pragma unroll
            for (int k = 0; k < 32; ++k) v[k] = 0.0f;
        }
        float sum = 0.0f, sq = 0.0f;
#pragma unroll
        for (int k = 0; k < 32; ++k) { sum += v[k]; sq += v[k] * v[k]; }
        sum += __shfl_xor(sum, 1); sq += __shfl_xor(sq, 1);
        sum += __shfl_xor(sum, 2); sq += __shfl_xor(sq, 2);
        const float mu = sum * (1.0f / 128.0f);
        const float var = sq * (1.0f / 128.0f) - mu * mu;
        const float rstd = rsqrtf(var + 1e-5f);
        if (ok) {
#pragma unroll
            for (int k = 0; k < 8; ++k) {
                const float4 gg = *(const float4*)(g + c0 + k * 4);
                const float4 bb = *(const float4*)(b + c0 + k * 4);
                v[k * 4 + 0] = (v[k * 4 + 0] - mu) * rstd * gg.x + bb.x;
                v[k * 4 + 1] = (v[k * 4 + 1] - mu) * rstd * gg.y + bb.y;
                v[k * 4 + 2] = (v[k * 4 + 2] - mu) * rstd * gg.z + bb.z;
                v[k * 4 + 3] = (v[k * 4 + 3] - mu) * rstd * gg.w + bb.w;
                *(float4*)(hg + (size_t)node * 128 + c0 + k * 4) =
                    make_float4(v[k * 4 + 0], v[k * 4 + 1], v[k * 4 + 2], v[k * 4 + 3]);
            }
#pragma unroll
            for (int q = 0; q < 4; ++q) {
                bf16x8 pk;
#pragma unroll
                for (int j = 0; j < 8; ++j) pk[j] = (bf16)v[q * 8 + j];
                *(bf16x8*)(hb + (size_t)node * 128 + c0 + q * 8) = pk;
                const int cc = (c0 >> 3) + q;
                *(bf16x8*)(hnL + row * 128 + ((cc ^ (row & 15)) << 3)) = pk;
            }
        } else {
#pragma unroll
            for (int q = 0; q < 4; ++q) {
                bf16x8 pk;
#pragma unroll
                for (int j = 0; j < 8; ++j) pk[j] = (bf16)0.0f;
                const int cc = (c0 >> 3) + q;
                *(bf16x8*)(hnL + row * 128 + ((cc ^ (row & 15)) << 3)) = pk;
            }
        }
    }
    __syncthreads();

    // phase 2: X-GEMM: X = h @ [W1a | W1b] (fp16 outputs)
    f32x4 accX[2][8] = {};
    for (int ks = 0; ks < 4; ++ks) {
        const int cb = ks * 4 + lgrp;
        bf16x8 a0 = *(const bf16x8*)(hnL + r0 * 128 + ((cb ^ (r0 & 15)) * 8));
        bf16x8 a1 = *(const bf16x8*)(hnL + r1 * 128 + ((cb ^ (r1 & 15)) * 8));
        const int k0 = ks * 32 + lgrp * 8;
#pragma unroll
        for (int ni = 0; ni < 8; ++ni) {
            const int col = wc * 128 + ni * 16 + lrow;
            bf16x8 bw = *(const bf16x8*)(W1abt + (size_t)col * 128 + k0);
            accX[0][ni] = __builtin_amdgcn_mfma_f32_16x16x32_bf16(a0, bw, accX[0][ni], 0, 0, 0);
            accX[1][ni] = __builtin_amdgcn_mfma_f32_16x16x32_bf16(a1, bw, accX[1][ni], 0, 0, 0);
        }
    }
#pragma unroll
    for (int mi = 0; mi < 2; ++mi) {
#pragma unroll
        for (int r = 0; r < 4; ++r) {
            const int row = wr * 32 + mi * 16 + lgrp * 4 + r;
            const int node = nb0 + row;
            if (node >= NN) continue;
#pragma unroll
            for (int ni = 0; ni < 8; ++ni) {
                const int col = wc * 128 + ni * 16 + lrow;
                float v = (mi == 0 ? accX[0][ni][r] : accX[1][ni][r]);
                if (col < 128) Xsh[(size_t)node * 128 + col] = __float2half(v);
                else Xdh[(size_t)node * 128 + (col - 128)] = __float2half(v);
            }
        }
    }
}

// ---------------------------------------------------------------- edge message kernel
__global__ __launch_bounds__(256) void edge_kernel(
    const int* __restrict__ su_s, const int* __restrict__ dst_s,
    const float* __restrict__ dist_s,
    const __half* __restrict__ Xsh, const __half* __restrict__ Xdh,
    const bf16* __restrict__ W1rt, const bf16* __restrict__ W2t,
    const float* __restrict__ b2, float* __restrict__ sums) {
    __shared__ char smem[33792];
    __half* xhL = (__half*)smem;             // [64][XPB] fp16 xsum (stage..epi1)
    bf16* msgL = (bf16*)(smem + 17408);      // [64][128] bf16 msg1 (epi1..GEMM2)
    float* m2f = (float*)smem;               // [64][M2P] fp32 msg2 (epi2..reduction)
    __shared__ int dstL[64];
    __shared__ int srcL[64];
    const int tid = threadIdx.x;
    const int lane = tid & 63, wave = tid >> 6;
    const int wr = wave >> 1, wc = wave & 1;
    const int lrow = lane & 15, lgrp = lane >> 4;
    const int eb = blockIdx.x * 64;

    const int r0 = wr * 32 + lrow;
    const int r1 = r0 + 16;
    const int e0 = eb + r0, e1 = eb + r1;
    const int ty0 = su_s[e0] >> 16, ty1 = su_s[e1] >> 16;
    const float di0 = dist_s[e0], di1 = dist_s[e1];
    if (tid < 64) { dstL[tid] = dst_s[eb + tid]; srcL[tid] = su_s[eb + tid] & 0xffff; }
    __syncthreads();

    // cooperative coalesced staging: xh[row][col] = Xsh[src[row]][col] + Xdh[dst[row]][col]
    // (native packed v_pk_add_f16 — no format conversion)
#pragma unroll
    for (int i = tid; i < 64 * 16; i += 256) {
        const int row = i >> 4, c8 = (i & 15) << 3;
        union { u32x4 v; __half2 h[4]; } A, B, S;
        A.v = *(const u32x4*)(Xsh + (size_t)srcL[row] * 128 + c8);
        B.v = *(const u32x4*)(Xdh + (size_t)dstL[row] * 128 + c8);
#pragma unroll
        for (int j = 0; j < 4; ++j) S.h[j] = __hadd2(A.h[j], B.h[j]);
        *(u32x4*)(xhL + row * XPB + c8) = S.v;
    }

    const float step = 6.0f / 31.0f;
    const float gamma = 1.0f / (step * step);

    // GEMM1 residual (registers only; overlaps staging latency)
    f32x4 acc[2][4] = {};
#pragma unroll
    for (int ks = 0; ks < 2; ++ks) {
        const int k0 = ks * 32 + lgrp * 8;
        bf16x8 a0, a1;
        if (k0 < 32) {
#pragma unroll
            for (int j = 0; j < 8; ++j) {
                float cj = (float)(k0 + j) * step;
                float v0 = di0 - cj, v1 = di1 - cj;
                a0[j] = (bf16)__expf(-gamma * v0 * v0);
                a1[j] = (bf16)__expf(-gamma * v1 * v1);
            }
        } else {
#pragma unroll
            for (int j = 0; j < 8; ++j) { a0[j] = (bf16)0.0f; a1[j] = (bf16)0.0f; }
            if (k0 == 32) {
                a0[0] = (bf16)di0; a1[0] = (bf16)di1;
                a0[1] = (bf16)1.0f; a1[1] = (bf16)1.0f;
                a0[2] = (bf16)(float)ty0; a1[2] = (bf16)(float)ty1;
            }
        }
#pragma unroll
        for (int ni = 0; ni < 4; ++ni) {
            const int col = wc * 64 + ni * 16 + lrow;
            bf16x8 b = *(const bf16x8*)(W1rt + (size_t)col * 64 + k0);
            acc[0][ni] = __builtin_amdgcn_mfma_f32_16x16x32_bf16(a0, b, acc[0][ni], 0, 0, 0);
            acc[1][ni] = __builtin_amdgcn_mfma_f32_16x16x32_bf16(a1, b, acc[1][ni], 0, 0, 0);
        }
    }
    __syncthreads();  // xhL staged

    // epilogue 1: v = acc + xh, silu -> msgL (bf16, XOR-swizzled 16B chunks)
#pragma unroll
    for (int mi = 0; mi < 2; ++mi) {
#pragma unroll
        for (int r = 0; r < 4; ++r) {
            const int row = wr * 32 + mi * 16 + lgrp * 4 + r;
            const __half* xr = xhL + row * XPB;
#pragma unroll
            for (int ni = 0; ni < 4; ++ni) {
                const int col = wc * 64 + ni * 16 + lrow;
                float v = (mi == 0 ? acc[0][ni][r] : acc[1][ni][r]) + __half2float(xr[col]);
                v = silu_f(v);
                const int cc = col >> 3;
                msgL[row * 128 + ((cc ^ (row & 15)) * 8) + (col & 7)] = (bf16)v;
            }
        }
    }
    __syncthreads();  // msgL ready; all xhL epi1-reads done

    f32x4 acc2[2][4] = {};
#pragma unroll
    for (int ks = 0; ks < 4; ++ks) {
        const int cb = ks * 4 + lgrp;
        bf16x8 a0 = *(const bf16x8*)(msgL + r0 * 128 + ((cb ^ (r0 & 15)) * 8));
        bf16x8 a1 = *(const bf16x8*)(msgL + r1 * 128 + ((cb ^ (r1 & 15)) * 8));
        const int k0 = ks * 32 + lgrp * 8;
#pragma unroll
        for (int ni = 0; ni < 4; ++ni) {
            const int col = wc * 64 + ni * 16 + lrow;
            bf16x8 b = *(const bf16x8*)(W2t + (size_t)col * 128 + k0);
            acc2[0][ni] = __builtin_amdgcn_mfma_f32_16x16x32_bf16(a0, b, acc2[0][ni], 0, 0, 0);
            acc2[1][ni] = __builtin_amdgcn_mfma_f32_16x16x32_bf16(a1, b, acc2[1][ni], 0, 0, 0);
        }
    }
    __syncthreads();  // all msg1 reads done; smem reusable as m2f

    // epilogue 2: silu(acc2+b2) -> m2f (fp32, no pack)
#pragma unroll
    for (int mi = 0; mi < 2; ++mi) {
#pragma unroll
        for (int ni = 0; ni < 4; ++ni) {
            const int col = wc * 64 + ni * 16 + lrow;
            const float bias = b2[col];
#pragma unroll
            for (int r = 0; r < 4; ++r) {
                const int row = wr * 32 + mi * 16 + lgrp * 4 + r;
                float v = silu_f((mi == 0 ? acc2[0][ni][r] : acc2[1][ni][r]) + bias);
                m2f[row * M2P + col] = v;
            }
        }
    }
    __syncthreads();
    // run-reduction over sorted dst (fp32 pairs)
    {
        const int cp = (tid & 63) * 2;
        const int q = tid >> 6;
        float a0s = 0.0f, a1s = 0.0f;
        int cur = dstL[q * 16];
        for (int i = 0; i < 16; ++i) {
            const int row = q * 16 + i;
            const int dd = dstL[row];
            if (dd != cur) {
                atomicAdd(&sums[(size_t)cur * 128 + cp], a0s);
                atomicAdd(&sums[(size_t)cur * 128 + cp + 1], a1s);
                a0s = 0.0f; a1s = 0.0f; cur = dd;
            }
            const float2 mv = *(const float2*)(m2f + row * M2P + cp);
            a0s += mv.x;
            a1s += mv.y;
        }
        atomicAdd(&sums[(size_t)cur * 128 + cp], a0s);
        atomicAdd(&sums[(size_t)cur * 128 + cp + 1], a1s);
    }
}

// ---------------------------------------------------------------- node update kernel (+fused next-layer X-GEMM)
__global__ __launch_bounds__(256) void node_kernel(
    float* __restrict__ hg, bf16* __restrict__ hb, float* __restrict__ sums,
    const int* __restrict__ cnt, const int* __restrict__ node_type,
    const bf16* __restrict__ U1t, const bf16* __restrict__ U2t,
    const float* __restrict__ ub1, const float* __restrict__ ub2,
    const float* __restrict__ ng, const float* __restrict__ nb_,
    const bf16* __restrict__ W1abt_next, __half* __restrict__ Xsh,
    __half* __restrict__ Xdh, int compute_x) {
    __shared__ char smem[49664];
    bf16* xL = (bf16*)smem;                 // [64][256] swizzled (phases 1-2)
    bf16* uL = (bf16*)(smem + 32768);       // [64][128] swizzled (phases 2-3)
    bf16* hnL = (bf16*)smem;                // [64][128] swizzled, offset 0 (phases 4-6)
    float* u2f = (float*)(smem + 16384);    // [64][129] fp32 (phases 4-5)
    const int tid = threadIdx.x;
    const int lane = tid & 63, wave = tid >> 6;
    const int wr = wave >> 1, wc = wave & 1;
    const int lrow = lane & 15, lgrp = lane >> 4;
    const int nb0 = blockIdx.x * 64;
    const int r0 = wr * 32 + lrow, r1 = r0 + 16;

    // phase 1: stage [h | agg] into xL; zero sums for next layer
    for (int i = tid; i < 64 * 32; i += 256) {
        const int row = i >> 5, cc = i & 31;
        const int node = nb0 + row;
        bf16x8 v;
        if (node < NN) {
            const int col8 = cc * 8;
            if (col8 < 128) {
                v = *(const bf16x8*)(hb + (size_t)node * 128 + col8);
            } else {
                const float inv = 1.0f / fmaxf((float)cnt[node], 1.0f);
                float4* p0 = (float4*)(sums + (size_t)node * 128 + (col8 - 128));
                float4* p1 = (float4*)(sums + (size_t)node * 128 + (col8 - 128) + 4);
                const float4 f0 = *p0;
                const float4 f1 = *p1;
                v[0] = (bf16)(f0.x * inv); v[1] = (bf16)(f0.y * inv);
                v[2] = (bf16)(f0.z * inv); v[3] = (bf16)(f0.w * inv);
                v[4] = (bf16)(f1.x * inv); v[5] = (bf16)(f1.y * inv);
                v[6] = (bf16)(f1.z * inv); v[7] = (bf16)(f1.w * inv);
                *p0 = make_float4(0.f, 0.f, 0.f, 0.f);
                *p1 = make_float4(0.f, 0.f, 0.f, 0.f);
            }
        } else {
#pragma unroll
            for (int j = 0; j < 8; ++j) v[j] = (bf16)0.0f;
        }
        *(bf16x8*)(xL + row * 256 + ((cc ^ (row & 15)) * 8)) = v;
    }
    __syncthreads();

    // phase 2: GEMM1 (K=256) -> silu -> uL
    f32x4 acc[2][4] = {};
    for (int ks = 0; ks < 8; ++ks) {
        const int cb = ks * 4 + lgrp;
        bf16x8 a0 = *(const bf16x8*)(xL + r0 * 256 + ((cb ^ (r0 & 15)) * 8));
        bf16x8 a1 = *(const bf16x8*)(xL + r1 * 256 + ((cb ^ (r1 & 15)) * 8));
        const int k0 = ks * 32 + lgrp * 8;
#pragma unroll
        for (int ni = 0; ni < 4; ++ni) {
            const int col = wc * 64 + ni * 16 + lrow;
            bf16x8 b = *(const bf16x8*)(U1t + (size_t)col * 256 + k0);
            acc[0][ni] = __builtin_amdgcn_mfma_f32_16x16x32_bf16(a0, b, acc[0][ni], 0, 0, 0);
            acc[1][ni] = __builtin_amdgcn_mfma_f32_16x16x32_bf16(a1, b, acc[1][ni], 0, 0, 0);
        }
    }
#pragma unroll
    for (int mi = 0; mi < 2; ++mi) {
#pragma unroll
        for (int ni = 0; ni < 4; ++ni) {
            const int col = wc * 64 + ni * 16 + lrow;
            const float bias = ub1[col];
            const int cc = col >> 3;
#pragma unroll
            for (int r = 0; r < 4; ++r) {
                const int row = wr * 32 + mi * 16 + lgrp * 4 + r;
                float v = silu_f((mi == 0 ? acc[0][ni][r] : acc[1][ni][r]) + bias);
                uL[row * 128 + ((cc ^ (row & 15)) * 8) + (col & 7)] = (bf16)v;
            }
        }
    }
    __syncthreads();

    // phase 3: GEMM2 (K=128)
    f32x4 acc2[2][4] = {};
    for (int ks = 0; ks < 4; ++ks) {
        const int cb = ks * 4 + lgrp;
        bf16x8 a0 = *(const bf16x8*)(uL + r0 * 128 + ((cb ^ (r0 & 15)) * 8));
        bf16x8 a1 = *(const bf16x8*)(uL + r1 * 128 + ((cb ^ (r1 & 15)) * 8));
        const int k0 = ks * 32 + lgrp * 8;
#pragma unroll
        for (int ni = 0; ni < 4; ++ni) {
            const int col = wc * 64 + ni * 16 + lrow;
            bf16x8 b = *(const bf16x8*)(U2t + (size_t)col * 128 + k0);
            acc2[0][ni] = __builtin_amdgcn_mfma_f32_16x16x32_bf16(a0, b, acc2[0][ni], 0, 0, 0);
            acc2[1][ni] = __builtin_amdgcn_mfma_f32_16x16x32_bf16(a1, b, acc2[1][ni], 0, 0, 0);
        }
    }
    __syncthreads();  // xL & uL dead from here; u2f/hnL regions become live

    // phase 4: u2f = acc2 + bias; cooperative old-h copy hb -> hnL (swizzled)
#pragma unroll
    for (int mi = 0; mi < 2; ++mi) {
#pragma unroll
        for (int ni = 0; ni < 4; ++ni) {
            const int col = wc * 64 + ni * 16 + lrow;
            const float bias = ub2[col];
#pragma unroll
            for (int r = 0; r < 4; ++r) {
                const int row = wr * 32 + mi * 16 + lgrp * 4 + r;
                u2f[row * 129 + col] = (mi == 0 ? acc2[0][ni][r] : acc2[1][ni][r]) + bias;
            }
        }
    }
    for (int i = tid; i < 64 * 16; i += 256) {
        const int row = i >> 4, cc = i & 15;
        const int node = nb0 + row;
        bf16x8 v;
        if (node < NN) v = *(const bf16x8*)(hb + (size_t)node * 128 + cc * 8);
        else { for (int j = 0; j < 8; ++j) v[j] = (bf16)0.0f; }
        *(bf16x8*)(hnL + row * 128 + ((cc ^ (row & 15)) * 8)) = v;
    }
    __syncthreads();

    // phase 5: LN tail (4 lanes/row); lig rows overwrite hnL + global h
    {
        const int row = tid >> 2, sl = tid & 3;
        const int node = nb0 + row;
        const bool lig = (node < NN) && (node_type[node] == 1);
        float sum = 0.0f, sq = 0.0f;
        if (lig) {
#pragma unroll
            for (int k = 0; k < 32; ++k) {
                const int c = sl + (k << 2);
                float s = hg[(size_t)node * 128 + c] + u2f[row * 129 + c];
                u2f[row * 129 + c] = s;
                sum += s; sq += s * s;
            }
        }
        sum += __shfl_xor(sum, 1); sq += __shfl_xor(sq, 1);
        sum += __shfl_xor(sum, 2); sq += __shfl_xor(sq, 2);
        if (lig) {
            const float mu = sum * (1.0f / 128.0f);
            const float var = sq * (1.0f / 128.0f) - mu * mu;
            const float rstd = rsqrtf(var + 1e-5f);
#pragma unroll
            for (int k = 0; k < 32; ++k) {
                const int c = sl + (k << 2);
                float s = u2f[row * 129 + c];
                float o = (s - mu) * rstd * ng[c] + nb_[c];
                hg[(size_t)node * 128 + c] = o;
                hb[(size_t)node * 128 + c] = (bf16)o;
                const int cc = c >> 3;
                hnL[row * 128 + ((cc ^ (row & 15)) << 3) + (c & 7)] = (bf16)o;
            }
        }
    }
    if (!compute_x) return;
    __syncthreads();

    // phase 6: next-layer X-GEMM: X = hnew @ [W1a | W1b] (fp16 outputs)
    f32x4 accX[2][8] = {};
    for (int ks = 0; ks < 4; ++ks) {
        const int cb = ks * 4 + lgrp;
        bf16x8 a0 = *(const bf16x8*)(hnL + r0 * 128 + ((cb ^ (r0 & 15)) * 8));
        bf16x8 a1 = *(const bf16x8*)(hnL + r1 * 128 + ((cb ^ (r1 & 15)) * 8));
        const int k0 = ks * 32 + lgrp * 8;
#pragma unroll
        for (int ni = 0; ni < 8; ++ni) {
            const int col = wc * 128 + ni * 16 + lrow;
            bf16x8 b = *(const bf16x8*)(W1abt_next + (size_t)col * 128 + k0);
            accX[0][ni] = __builtin_amdgcn_mfma_f32_16x16x32_bf16(a0, b, accX[0][ni], 0, 0, 0);
            accX[1][ni] = __builtin_amdgcn_mfma_f32_16x16x32_bf16(a1, b, accX[1][ni], 0, 0, 0);
        }
    }
#pragma unroll
    for (int mi = 0; mi < 2; ++mi) {
#pragma unroll
        for (int r = 0; r < 4; ++r) {
            const int row = wr * 32 + mi * 16 + lgrp * 4 + r;
            const int node = nb0 + row;
            if (node >= NN) continue;
#pragma unroll
            for (int ni = 0; ni < 8; ++ni) {
                const int col = wc * 128 + ni * 16 + lrow;
                float v = (mi == 0 ? accX[0][ni][r] : accX[1][ni][r]);
                if (col < 128) Xsh[(size_t)node * 128 + col] = __float2half(v);
                else Xdh[(size_t)node * 128 + (col - 128)] = __float2half(v);
            }
        }
    }
}

// ---------------------------------------------------------------- pooling + head
__global__ void pool_kernel(const int* __restrict__ nt, const int* __restrict__ batch,
                            const float* __restrict__ hg, float* __restrict__ gsum,
                            float* __restrict__ gcnt) {
    int idx = blockIdx.x * 256 + threadIdx.x;
    int n = idx >> 7, c = idx & 127;
    if (n >= NN) return;
    if (nt[n] == 1) {
        int b = batch[n];
        atomicAdd(&gsum[b * 128 + c], hg[(size_t)n * 128 + c]);
        if (c == 0) atomicAdd(&gcnt[b], 1.0f);
    }
}

__global__ void head_kernel(const float* __restrict__ gsum, const float* __restrict__ gcnt,
                            const float* __restrict__ w1, const float* __restrict__ b1,
                            const float* __restrict__ w2, const float* __restrict__ b2,
                            float* __restrict__ out) {
    int g = blockIdx.x, c = threadIdx.x;  // 128 threads
    __shared__ float gfL[128], uH[128];
    float inv = 1.0f / fmaxf(gcnt[g], 1.0f);
    gfL[c] = gsum[g * 128 + c] * inv;
    __syncthreads();
    float acc = b1[c];
    for (int k = 0; k < 128; ++k) acc += gfL[k] * w1[k * 128 + c];
    uH[c] = silu_f(acc);
    __syncthreads();
    gfL[c] = uH[c] * w2[c];
    __syncthreads();
    for (int s = 64; s > 0; s >>= 1) { if (c < s) gfL[c] += gfL[c + s]; __syncthreads(); }
    if (c == 0) out[g] = gfL[0] + b2[0];
}

// ---------------------------------------------------------------- launch
extern "C" void kernel_launch(void* const* d_in, const int* in_sizes, int n_in,
                              void* d_out, int out_size, void* d_ws, size_t ws_size,
                              hipStream_t stream) {
    const int* z = (const int*)d_in[0];
    const int* node_type = (const int*)d_in[1];
    const float* pos = (const float*)d_in[2];
    const int* edge_index = (const int*)d_in[3];
    const int* edge_type = (const int*)d_in[4];
    const int* batch = (const int*)d_in[5];
    const float* t_in = (const float*)d_in[6];
    const float* emb_z = (const float*)d_in[7];
    const float* emb_nt = (const float*)d_in[8];
    const float* in_norm_g = (const float*)d_in[9];
    const float* in_norm_b = (const float*)d_in[10];
    const float* time_w1 = (const float*)d_in[11];
    const float* time_b1 = (const float*)d_in[12];
    const float* time_w2 = (const float*)d_in[13];
    const float* time_b2 = (const float*)d_in[14];
    const float* l_edge_emb = (const float*)d_in[15];
    const float* l_msg_w1 = (const float*)d_in[16];
    const float* l_msg_b1 = (const float*)d_in[17];
    const float* l_msg_w2 = (const float*)d_in[18];
    const float* l_msg_b2 = (const float*)d_in[19];
    const float* l_upd_w1 = (const float*)d_in[20];
    const float* l_upd_b1 = (const float*)d_in[21];
    const float* l_upd_w2 = (const float*)d_in[22];
    const float* l_upd_b2 = (const float*)d_in[23];
    const float* l_norm_g = (const float*)d_in[24];
    const float* l_norm_b = (const float*)d_in[25];
    const float* head_w1 = (const float*)d_in[26];
    const float* head_b1 = (const float*)d_in[27];
    const float* head_w2 = (const float*)d_in[28];
    const float* head_b2 = (const float*)d_in[29];
    float* out = (float*)d_out;

    char* w = (char*)d_ws;
    auto alloc = [&](size_t bytes) {
        char* p = w;
        w += (bytes + 255) & ~(size_t)255;
        return p;
    };
    float* hg = (float*)alloc((size_t)NN * 128 * 4);
    bf16* hb = (bf16*)alloc((size_t)NN * 128 * 2);
    float* sums = (float*)alloc((size_t)NN * 128 * 4);
    __half* Xsh = (__half*)alloc((size_t)NN * 128 * 2);
    __half* Xdh = (__half*)alloc((size_t)NN * 128 * 2);
    int* cnt = (int*)alloc((size_t)NN * 4);
    int* cursor = (int*)alloc((size_t)NN * 4);
    int* su_s = (int*)alloc((size_t)EE * 4);
    int* dst_s = (int*)alloc((size_t)EE * 4);
    float* dist_s = (float*)alloc((size_t)EE * 4);
    float* dist_raw = (float*)alloc((size_t)EE * 4);
    bf16* W1abt = (bf16*)alloc((size_t)4 * 256 * 128 * 2);
    bf16* W1rt = (bf16*)alloc((size_t)4 * 128 * 64 * 2);
    bf16* W2t = (bf16*)alloc((size_t)4 * 128 * 128 * 2);
    bf16* U1t = (bf16*)alloc((size_t)4 * 128 * 256 * 2);
    bf16* U2t = (bf16*)alloc((size_t)4 * 128 * 128 * 2);
    float* tf = (float*)alloc((size_t)GG * 128 * 4);
    float* gsum = (float*)alloc((size_t)GG * 128 * 4);
    float* gcnt = (float*)alloc((size_t)GG * 4);

    hipMemsetAsync(cnt, 0, (size_t)NN * 4, stream);
    hipMemsetAsync(sums, 0, (size_t)NN * 128 * 4, stream);  // node_kernel re-zeros per layer
    prep_weights<<<1664, 256, 0, stream>>>(l_msg_w1, l_msg_w2, l_upd_w1, l_upd_w2,
                                           l_edge_emb, l_msg_b1, W1abt, W1rt, W2t, U1t, U2t);
    time_mlp<<<GG, 128, 0, stream>>>(t_in, time_w1, time_b1, time_w2, time_b2, tf);
    edge_pre<<<(EE + 255) / 256, 256, 0, stream>>>(edge_index, pos, dist_raw, cnt);
    scan_kernel<<<1, 1024, 0, stream>>>(cnt, cursor);
    scatter_kernel<<<(EE + 255) / 256, 256, 0, stream>>>(edge_index, edge_type, dist_raw,
                                                         cursor, su_s, dst_s, dist_s);
    node_init_fused<<<(NN + 63) / 64, 256, 0, stream>>>(
        z, node_type, batch, tf, emb_z, emb_nt, in_norm_g, in_norm_b,
        hg, hb, W1abt, Xsh, Xdh);
    for (int l = 0; l < 4; ++l) {
        edge_kernel<<<EE / 64, 256, 0, stream>>>(
            su_s, dst_s, dist_s, Xsh, Xdh, W1rt + (size_t)l * 8192,
            W2t + (size_t)l * 16384, l_msg_b2 + l * 128, sums);
        const int nl = (l < 3) ? (l + 1) : 0;
        node_kernel<<<(NN + 63) / 64, 256, 0, stream>>>(
            hg, hb, sums, cnt, node_type, U1t + (size_t)l * 32768, U2t + (size_t)l * 16384,
            l_upd_b1 + l * 128, l_upd_b2 + l * 128, l_norm_g + l * 128, l_norm_b + l * 128,
            W1abt + (size_t)nl * 32768, Xsh, Xdh, (l < 3) ? 1 : 0);
    }
    hipMemsetAsync(gsum, 0, (size_t)GG * 128 * 4, stream);
    hipMemsetAsync(gcnt, 0, (size_t)GG * 4, stream);
    pool_kernel<<<(NN * 128 + 255) / 256, 256, 0, stream>>>(node_type, batch, hg, gsum, gcnt);
    head_kernel<<<GG, 128, 0, stream>>>(gsum, gcnt, head_w1, head_b1, head_w2, head_b2, out);
}

// Round 13
// 1373.599 us; speedup vs baseline: 1.1110x; 1.1110x over previous
//
#include <hip/hip_runtime.h>
#include <hip/hip_bf16.h>

#define NN 50000
#define EE 800000
#define GG 128
#define HH 128
#define XPB 136   // bf16 LDS pitch: 272B rows -> 16B-aligned, <=2-way banks in epi1

typedef __bf16 bf16;
typedef __attribute__((ext_vector_type(8))) __bf16 bf16x8;
typedef __attribute__((ext_vector_type(4))) float f32x4;

__device__ __forceinline__ float silu_f(float x) { return x / (1.0f + __expf(-x)); }

// ---------------------------------------------------------------- weights prep
__global__ void prep_weights(const float* __restrict__ w1, const float* __restrict__ w2,
                             const float* __restrict__ u1, const float* __restrict__ u2,
                             const float* __restrict__ ee, const float* __restrict__ mb1,
                             bf16* __restrict__ W1abt, bf16* __restrict__ W1rt,
                             bf16* __restrict__ W2t, bf16* __restrict__ U1t,
                             bf16* __restrict__ U2t) {
    int idx = blockIdx.x * 256 + threadIdx.x;
    if (idx < 131072) {                        // W1abt: 4*256*128
        int l = idx >> 15, rem = idx & 32767;
        int c = rem >> 7, k = rem & 127;
        int krow = k + ((c >= 128) ? 128 : 0);
        W1abt[idx] = (bf16)w1[(size_t)l * 417 * 128 + (size_t)krow * 128 + (c & 127)];
    } else if ((idx -= 131072) < 32768) {      // W1rt: 4*128*64
        int l = idx >> 13, rem = idx & 8191;
        int c = rem >> 6, k = rem & 63;
        const float* w1l = w1 + (size_t)l * 417 * 128;
        float v = 0.0f;
        if (k < 32) v = w1l[(size_t)(384 + k) * 128 + c];
        else if (k == 32) v = w1l[(size_t)416 * 128 + c];
        else if (k == 33) {
            v = mb1[l * 128 + c];
            for (int t = 0; t < 128; ++t)
                v += ee[(size_t)l * 256 + t] * w1l[(size_t)(256 + t) * 128 + c];
        } else if (k == 34) {
            for (int t = 0; t < 128; ++t)
                v += (ee[(size_t)l * 256 + 128 + t] - ee[(size_t)l * 256 + t]) *
                     w1l[(size_t)(256 + t) * 128 + c];
        }
        W1rt[idx] = (bf16)v;
    } else if ((idx -= 32768) < 65536) {       // W2t
        int l = idx / 16384, rem = idx % 16384;
        int n = rem / 128, k = rem % 128;
        W2t[idx] = (bf16)w2[(size_t)l * 16384 + (size_t)k * 128 + n];
    } else if ((idx -= 65536) < 131072) {      // U1t ; u1 is [4][256][128]
        int l = idx / 32768, rem = idx % 32768;
        int n = rem / 256, k = rem % 256;
        U1t[idx] = (bf16)u1[(size_t)l * 32768 + (size_t)k * 128 + n];
    } else if ((idx -= 131072) < 65536) {      // U2t ; u2 is [4][128][128]
        int l = idx / 16384, rem = idx % 16384;
        int n = rem / 128, k = rem % 128;
        U2t[idx] = (bf16)u2[(size_t)l * 16384 + (size_t)k * 128 + n];
    }
}

// ---------------------------------------------------------------- time MLP
__global__ void time_mlp(const float* __restrict__ t, const float* __restrict__ w1,
                         const float* __restrict__ b1, const float* __restrict__ w2,
                         const float* __restrict__ b2, float* __restrict__ tf) {
    int g = blockIdx.x, c = threadIdx.x;  // 128 threads
    __shared__ float sL[64], uT[128];
    float tv = t[g];
    if (c < 32) {
        float fr = expf(-(float)c * (logf(10000.0f) / 31.0f));
        float arg = tv * fr;
        sL[c] = sinf(arg);
        sL[c + 32] = cosf(arg);
    }
    __syncthreads();
    float acc = b1[c];
    for (int k = 0; k < 64; ++k) acc += sL[k] * w1[k * 128 + c];
    uT[c] = silu_f(acc);
    __syncthreads();
    float acc2 = b2[c];
    for (int k = 0; k < 128; ++k) acc2 += uT[k] * w2[k * 128 + c];
    tf[g * 128 + c] = acc2;
}

// ---------------------------------------------------------------- edge preprocess
__global__ void edge_pre(const int* __restrict__ ei, const float* __restrict__ pos,
                         float* __restrict__ dist_raw, int* __restrict__ cnt) {
    int e = blockIdx.x * 256 + threadIdx.x;
    if (e >= EE) return;
    int s = ei[e], d = ei[EE + e];
    float dx = pos[s * 3 + 0] - pos[d * 3 + 0];
    float dy = pos[s * 3 + 1] - pos[d * 3 + 1];
    float dz = pos[s * 3 + 2] - pos[d * 3 + 2];
    dist_raw[e] = sqrtf(dx * dx + dy * dy + dz * dz);
    atomicAdd(&cnt[d], 1);
}

__global__ void scan_kernel(const int* __restrict__ cnt, int* __restrict__ cursor) {
    __shared__ int part[1024];
    int t = threadIdx.x;
    const int per = (NN + 1023) / 1024;
    int start = t * per, end = min(start + per, NN);
    int s = 0;
    for (int i = start; i < end; ++i) s += cnt[i];
    part[t] = s;
    __syncthreads();
    for (int off = 1; off < 1024; off <<= 1) {
        int v = (t >= off) ? part[t - off] : 0;
        __syncthreads();
        part[t] += v;
        __syncthreads();
    }
    int base = (t == 0) ? 0 : part[t - 1];
    for (int i = start; i < end; ++i) { cursor[i] = base; base += cnt[i]; }
}

// packs src (16b) | type (bit 16) into su_s
__global__ void scatter_kernel(const int* __restrict__ ei, const int* __restrict__ et,
                               const float* __restrict__ dist_raw, int* __restrict__ cursor,
                               int* __restrict__ su_s, int* __restrict__ dst_s,
                               float* __restrict__ dist_s) {
    int e = blockIdx.x * 256 + threadIdx.x;
    if (e >= EE) return;
    int d = ei[EE + e];
    int p = atomicAdd(&cursor[d], 1);
    su_s[p] = ei[e] | (et[e] << 16);
    dst_s[p] = d;
    dist_s[p] = dist_raw[e];
}

// ---------------------------------------------------------------- node init + LN + X-GEMM (fused)
__global__ __launch_bounds__(256) void node_init_fused(
    const int* __restrict__ z, const int* __restrict__ nt, const int* __restrict__ batch,
    const float* __restrict__ tf, const float* __restrict__ emb_z,
    const float* __restrict__ emb_nt, const float* __restrict__ g,
    const float* __restrict__ b, float* __restrict__ hg, bf16* __restrict__ hb,
    const bf16* __restrict__ W1abt, bf16* __restrict__ Xsb, bf16* __restrict__ Xdb) {
    __shared__ bf16 hnL[64 * 128];   // swizzled chunks
    const int tid = threadIdx.x;
    const int lane = tid & 63, wave = tid >> 6;
    const int wr = wave >> 1, wc = wave & 1;
    const int lrow = lane & 15, lgrp = lane >> 4;
    const int nb0 = blockIdx.x * 64;
    const int r0 = wr * 32 + lrow, r1 = r0 + 16;

    // phase 1: build h, LN, write out, stage into hnL
    {
        const int row = tid >> 2, sl = tid & 3;
        const int node = nb0 + row;
        const bool ok = node < NN;
        const int c0 = sl * 32;
        float v[32];
        if (ok) {
            const int zz = min(max(z[node], 0), 127);
            const float* ez = emb_z + (size_t)zz * 128 + c0;
            const float* en = emb_nt + (size_t)nt[node] * 128 + c0;
            const float* tp = tf + (size_t)batch[node] * 128 + c0;
#pragma unroll
            for (int k = 0; k < 8; ++k) {
                const float4 a = *(const float4*)(ez + k * 4);
                const float4 c_ = *(const float4*)(en + k * 4);
                const float4 d_ = *(const float4*)(tp + k * 4);
                v[k * 4 + 0] = a.x + c_.x + d_.x;
                v[k * 4 + 1] = a.y + c_.y + d_.y;
                v[k * 4 + 2] = a.z + c_.z + d_.z;
                v[k * 4 + 3] = a.w + c_.w + d_.w;
            }
        } else {
#pragma unroll
            for (int k = 0; k < 32; ++k) v[k] = 0.0f;
        }
        float sum = 0.0f, sq = 0.0f;
#pragma unroll
        for (int k = 0; k < 32; ++k) { sum += v[k]; sq += v[k] * v[k]; }
        sum += __shfl_xor(sum, 1); sq += __shfl_xor(sq, 1);
        sum += __shfl_xor(sum, 2); sq += __shfl_xor(sq, 2);
        const float mu = sum * (1.0f / 128.0f);
        const float var = sq * (1.0f / 128.0f) - mu * mu;
        const float rstd = rsqrtf(var + 1e-5f);
        if (ok) {
#pragma unroll
            for (int k = 0; k < 8; ++k) {
                const float4 gg = *(const float4*)(g + c0 + k * 4);
                const float4 bb = *(const float4*)(b + c0 + k * 4);
                v[k * 4 + 0] = (v[k * 4 + 0] - mu) * rstd * gg.x + bb.x;
                v[k * 4 + 1] = (v[k * 4 + 1] - mu) * rstd * gg.y + bb.y;
                v[k * 4 + 2] = (v[k * 4 + 2] - mu) * rstd * gg.z + bb.z;
                v[k * 4 + 3] = (v[k * 4 + 3] - mu) * rstd * gg.w + bb.w;
                *(float4*)(hg + (size_t)node * 128 + c0 + k * 4) =
                    make_float4(v[k * 4 + 0], v[k * 4 + 1], v[k * 4 + 2], v[k * 4 + 3]);
            }
#pragma unroll
            for (int q = 0; q < 4; ++q) {
                bf16x8 pk;
#pragma unroll
                for (int j = 0; j < 8; ++j) pk[j] = (bf16)v[q * 8 + j];
                *(bf16x8*)(hb + (size_t)node * 128 + c0 + q * 8) = pk;
                const int cc = (c0 >> 3) + q;
                *(bf16x8*)(hnL + row * 128 + ((cc ^ (row & 15)) << 3)) = pk;
            }
        } else {
#pragma unroll
            for (int q = 0; q < 4; ++q) {
                bf16x8 pk;
#pragma unroll
                for (int j = 0; j < 8; ++j) pk[j] = (bf16)0.0f;
                const int cc = (c0 >> 3) + q;
                *(bf16x8*)(hnL + row * 128 + ((cc ^ (row & 15)) << 3)) = pk;
            }
        }
    }
    __syncthreads();

    // phase 2: X-GEMM: X = h @ [W1a | W1b]
    f32x4 accX[2][8] = {};
    for (int ks = 0; ks < 4; ++ks) {
        const int cb = ks * 4 + lgrp;
        bf16x8 a0 = *(const bf16x8*)(hnL + r0 * 128 + ((cb ^ (r0 & 15)) * 8));
        bf16x8 a1 = *(const bf16x8*)(hnL + r1 * 128 + ((cb ^ (r1 & 15)) * 8));
        const int k0 = ks * 32 + lgrp * 8;
#pragma unroll
        for (int ni = 0; ni < 8; ++ni) {
            const int col = wc * 128 + ni * 16 + lrow;
            bf16x8 bw = *(const bf16x8*)(W1abt + (size_t)col * 128 + k0);
            accX[0][ni] = __builtin_amdgcn_mfma_f32_16x16x32_bf16(a0, bw, accX[0][ni], 0, 0, 0);
            accX[1][ni] = __builtin_amdgcn_mfma_f32_16x16x32_bf16(a1, bw, accX[1][ni], 0, 0, 0);
        }
    }
#pragma unroll
    for (int mi = 0; mi < 2; ++mi) {
#pragma unroll
        for (int r = 0; r < 4; ++r) {
            const int row = wr * 32 + mi * 16 + lgrp * 4 + r;
            const int node = nb0 + row;
            if (node >= NN) continue;
#pragma unroll
            for (int ni = 0; ni < 8; ++ni) {
                const int col = wc * 128 + ni * 16 + lrow;
                float v = (mi == 0 ? accX[0][ni][r] : accX[1][ni][r]);
                if (col < 128) Xsb[(size_t)node * 128 + col] = (bf16)v;
                else Xdb[(size_t)node * 128 + (col - 128)] = (bf16)v;
            }
        }
    }
}

// ---------------------------------------------------------------- edge message kernel (R5 structure)
__global__ __launch_bounds__(256) void edge_kernel(
    const int* __restrict__ su_s, const int* __restrict__ dst_s,
    const float* __restrict__ dist_s,
    const bf16* __restrict__ Xsb, const bf16* __restrict__ Xdb,
    const bf16* __restrict__ W1rt, const bf16* __restrict__ W2t,
    const float* __restrict__ b2, float* __restrict__ sums) {
    __shared__ bf16 xbL[64 * XPB];     // 17.4KB: bf16 xsum, later bf16 msg2
    __shared__ bf16 msgL[64 * 128];    // 16KB: bf16 msg1 (GEMM2 A operand)
    __shared__ int dstL[64];
    __shared__ int srcL[64];
    const int tid = threadIdx.x;
    const int lane = tid & 63, wave = tid >> 6;
    const int wr = wave >> 1, wc = wave & 1;
    const int lrow = lane & 15, lgrp = lane >> 4;
    const int eb = blockIdx.x * 64;

    const int r0 = wr * 32 + lrow;
    const int r1 = r0 + 16;
    const int e0 = eb + r0, e1 = eb + r1;
    const int ty0 = su_s[e0] >> 16, ty1 = su_s[e1] >> 16;
    const float di0 = dist_s[e0], di1 = dist_s[e1];
    if (tid < 64) { dstL[tid] = dst_s[eb + tid]; srcL[tid] = su_s[eb + tid] & 0xffff; }
    __syncthreads();

    // cooperative coalesced staging: xb[row][col] = bf16(Xsb[src[row]][col] + Xdb[dst[row]][col])
#pragma unroll
    for (int i = tid; i < 64 * 16; i += 256) {
        const int row = i >> 4, c8 = (i & 15) << 3;
        bf16x8 a = *(const bf16x8*)(Xsb + (size_t)srcL[row] * 128 + c8);
        bf16x8 b = *(const bf16x8*)(Xdb + (size_t)dstL[row] * 128 + c8);
        bf16x8 s;
#pragma unroll
        for (int j = 0; j < 8; ++j) s[j] = (bf16)((float)a[j] + (float)b[j]);
        *(bf16x8*)(xbL + row * XPB + c8) = s;
    }

    const float step = 6.0f / 31.0f;
    const float gamma = 1.0f / (step * step);

    // GEMM1 residual (registers only; overlaps staging latency)
    f32x4 acc[2][4] = {};
#pragma unroll
    for (int ks = 0; ks < 2; ++ks) {
        const int k0 = ks * 32 + lgrp * 8;
        bf16x8 a0, a1;
        if (k0 < 32) {
#pragma unroll
            for (int j = 0; j < 8; ++j) {
                float cj = (float)(k0 + j) * step;
                float v0 = di0 - cj, v1 = di1 - cj;
                a0[j] = (bf16)__expf(-gamma * v0 * v0);
                a1[j] = (bf16)__expf(-gamma * v1 * v1);
            }
        } else {
#pragma unroll
            for (int j = 0; j < 8; ++j) { a0[j] = (bf16)0.0f; a1[j] = (bf16)0.0f; }
            if (k0 == 32) {
                a0[0] = (bf16)di0; a1[0] = (bf16)di1;
                a0[1] = (bf16)1.0f; a1[1] = (bf16)1.0f;
                a0[2] = (bf16)(float)ty0; a1[2] = (bf16)(float)ty1;
            }
        }
#pragma unroll
        for (int ni = 0; ni < 4; ++ni) {
            const int col = wc * 64 + ni * 16 + lrow;
            bf16x8 b = *(const bf16x8*)(W1rt + (size_t)col * 64 + k0);
            acc[0][ni] = __builtin_amdgcn_mfma_f32_16x16x32_bf16(a0, b, acc[0][ni], 0, 0, 0);
            acc[1][ni] = __builtin_amdgcn_mfma_f32_16x16x32_bf16(a1, b, acc[1][ni], 0, 0, 0);
        }
    }
    __syncthreads();  // xbL staged

    // epilogue 1: v = acc + xb, silu -> msgL (bf16, XOR-swizzled 16B chunks)
#pragma unroll
    for (int mi = 0; mi < 2; ++mi) {
#pragma unroll
        for (int r = 0; r < 4; ++r) {
            const int row = wr * 32 + mi * 16 + lgrp * 4 + r;
            const bf16* xr = xbL + row * XPB;
#pragma unroll
            for (int ni = 0; ni < 4; ++ni) {
                const int col = wc * 64 + ni * 16 + lrow;
                float v = (mi == 0 ? acc[0][ni][r] : acc[1][ni][r]) + (float)xr[col];
                v = silu_f(v);
                const int cc = col >> 3;
                msgL[row * 128 + ((cc ^ (row & 15)) * 8) + (col & 7)] = (bf16)v;
            }
        }
    }
    __syncthreads();  // msgL ready; all xbL epi1-reads done

    f32x4 acc2[2][4] = {};
#pragma unroll
    for (int ks = 0; ks < 4; ++ks) {
        const int cb = ks * 4 + lgrp;
        bf16x8 a0 = *(const bf16x8*)(msgL + r0 * 128 + ((cb ^ (r0 & 15)) * 8));
        bf16x8 a1 = *(const bf16x8*)(msgL + r1 * 128 + ((cb ^ (r1 & 15)) * 8));
        const int k0 = ks * 32 + lgrp * 8;
#pragma unroll
        for (int ni = 0; ni < 4; ++ni) {
            const int col = wc * 64 + ni * 16 + lrow;
            bf16x8 b = *(const bf16x8*)(W2t + (size_t)col * 128 + k0);
            acc2[0][ni] = __builtin_amdgcn_mfma_f32_16x16x32_bf16(a0, b, acc2[0][ni], 0, 0, 0);
            acc2[1][ni] = __builtin_amdgcn_mfma_f32_16x16x32_bf16(a1, b, acc2[1][ni], 0, 0, 0);
        }
    }
    // epilogue 2: silu(acc2+b2) -> xbL (bf16; all epi1 reads completed at last barrier)
#pragma unroll
    for (int mi = 0; mi < 2; ++mi) {
#pragma unroll
        for (int ni = 0; ni < 4; ++ni) {
            const int col = wc * 64 + ni * 16 + lrow;
            const float bias = b2[col];
#pragma unroll
            for (int r = 0; r < 4; ++r) {
                const int row = wr * 32 + mi * 16 + lgrp * 4 + r;
                float v = silu_f((mi == 0 ? acc2[0][ni][r] : acc2[1][ni][r]) + bias);
                xbL[row * XPB + col] = (bf16)v;
            }
        }
    }
    __syncthreads();
    // run-reduction over sorted dst (bf16 pairs -> fp32 accum)
    {
        const int cp = (tid & 63) * 2;
        const int q = tid >> 6;
        float a0s = 0.0f, a1s = 0.0f;
        int cur = dstL[q * 16];
        for (int i = 0; i < 16; ++i) {
            const int row = q * 16 + i;
            const int dd = dstL[row];
            if (dd != cur) {
                atomicAdd(&sums[(size_t)cur * 128 + cp], a0s);
                atomicAdd(&sums[(size_t)cur * 128 + cp + 1], a1s);
                a0s = 0.0f; a1s = 0.0f; cur = dd;
            }
            const unsigned u = *(const unsigned*)(xbL + row * XPB + cp);
            a0s += __uint_as_float(u << 16);
            a1s += __uint_as_float(u & 0xffff0000u);
        }
        atomicAdd(&sums[(size_t)cur * 128 + cp], a0s);
        atomicAdd(&sums[(size_t)cur * 128 + cp + 1], a1s);
    }
}

// ---------------------------------------------------------------- node update kernel (+fused next-layer X-GEMM)
__global__ __launch_bounds__(256) void node_kernel(
    float* __restrict__ hg, bf16* __restrict__ hb, float* __restrict__ sums,
    const int* __restrict__ cnt, const int* __restrict__ node_type,
    const bf16* __restrict__ U1t, const bf16* __restrict__ U2t,
    const float* __restrict__ ub1, const float* __restrict__ ub2,
    const float* __restrict__ ng, const float* __restrict__ nb_,
    const bf16* __restrict__ W1abt_next, bf16* __restrict__ Xsb,
    bf16* __restrict__ Xdb, int compute_x) {
    __shared__ char smem[49664];
    bf16* xL = (bf16*)smem;                 // [64][256] swizzled (phases 1-2)
    bf16* uL = (bf16*)(smem + 32768);       // [64][128] swizzled (phases 2-3)
    bf16* hnL = (bf16*)smem;                // [64][128] swizzled, offset 0 (phases 4-6)
    float* u2f = (float*)(smem + 16384);    // [64][129] fp32 (phases 4-5)
    const int tid = threadIdx.x;
    const int lane = tid & 63, wave = tid >> 6;
    const int wr = wave >> 1, wc = wave & 1;
    const int lrow = lane & 15, lgrp = lane >> 4;
    const int nb0 = blockIdx.x * 64;
    const int r0 = wr * 32 + lrow, r1 = r0 + 16;

    // phase 1: stage [h | agg] into xL; zero sums for next layer
    for (int i = tid; i < 64 * 32; i += 256) {
        const int row = i >> 5, cc = i & 31;
        const int node = nb0 + row;
        bf16x8 v;
        if (node < NN) {
            const int col8 = cc * 8;
            if (col8 < 128) {
                v = *(const bf16x8*)(hb + (size_t)node * 128 + col8);
            } else {
                const float inv = 1.0f / fmaxf((float)cnt[node], 1.0f);
                float4* p0 = (float4*)(sums + (size_t)node * 128 + (col8 - 128));
                float4* p1 = (float4*)(sums + (size_t)node * 128 + (col8 - 128) + 4);
                const float4 f0 = *p0;
                const float4 f1 = *p1;
                v[0] = (bf16)(f0.x * inv); v[1] = (bf16)(f0.y * inv);
                v[2] = (bf16)(f0.z * inv); v[3] = (bf16)(f0.w * inv);
                v[4] = (bf16)(f1.x * inv); v[5] = (bf16)(f1.y * inv);
                v[6] = (bf16)(f1.z * inv); v[7] = (bf16)(f1.w * inv);
                *p0 = make_float4(0.f, 0.f, 0.f, 0.f);
                *p1 = make_float4(0.f, 0.f, 0.f, 0.f);
            }
        } else {
#pragma unroll
            for (int j = 0; j < 8; ++j) v[j] = (bf16)0.0f;
        }
        *(bf16x8*)(xL + row * 256 + ((cc ^ (row & 15)) * 8)) = v;
    }
    __syncthreads();

    // phase 2: GEMM1 (K=256) -> silu -> uL
    f32x4 acc[2][4] = {};
    for (int ks = 0; ks < 8; ++ks) {
        const int cb = ks * 4 + lgrp;
        bf16x8 a0 = *(const bf16x8*)(xL + r0 * 256 + ((cb ^ (r0 & 15)) * 8));
        bf16x8 a1 = *(const bf16x8*)(xL + r1 * 256 + ((cb ^ (r1 & 15)) * 8));
        const int k0 = ks * 32 + lgrp * 8;
#pragma unroll
        for (int ni = 0; ni < 4; ++ni) {
            const int col = wc * 64 + ni * 16 + lrow;
            bf16x8 b = *(const bf16x8*)(U1t + (size_t)col * 256 + k0);
            acc[0][ni] = __builtin_amdgcn_mfma_f32_16x16x32_bf16(a0, b, acc[0][ni], 0, 0, 0);
            acc[1][ni] = __builtin_amdgcn_mfma_f32_16x16x32_bf16(a1, b, acc[1][ni], 0, 0, 0);
        }
    }
#pragma unroll
    for (int mi = 0; mi < 2; ++mi) {
#pragma unroll
        for (int ni = 0; ni < 4; ++ni) {
            const int col = wc * 64 + ni * 16 + lrow;
            const float bias = ub1[col];
            const int cc = col >> 3;
#pragma unroll
            for (int r = 0; r < 4; ++r) {
                const int row = wr * 32 + mi * 16 + lgrp * 4 + r;
                float v = silu_f((mi == 0 ? acc[0][ni][r] : acc[1][ni][r]) + bias);
                uL[row * 128 + ((cc ^ (row & 15)) * 8) + (col & 7)] = (bf16)v;
            }
        }
    }
    __syncthreads();

    // phase 3: GEMM2 (K=128)
    f32x4 acc2[2][4] = {};
    for (int ks = 0; ks < 4; ++ks) {
        const int cb = ks * 4 + lgrp;
        bf16x8 a0 = *(const bf16x8*)(uL + r0 * 128 + ((cb ^ (r0 & 15)) * 8));
        bf16x8 a1 = *(const bf16x8*)(uL + r1 * 128 + ((cb ^ (r1 & 15)) * 8));
        const int k0 = ks * 32 + lgrp * 8;
#pragma unroll
        for (int ni = 0; ni < 4; ++ni) {
            const int col = wc * 64 + ni * 16 + lrow;
            bf16x8 b = *(const bf16x8*)(U2t + (size_t)col * 128 + k0);
            acc2[0][ni] = __builtin_amdgcn_mfma_f32_16x16x32_bf16(a0, b, acc2[0][ni], 0, 0, 0);
            acc2[1][ni] = __builtin_amdgcn_mfma_f32_16x16x32_bf16(a1, b, acc2[1][ni], 0, 0, 0);
        }
    }
    __syncthreads();  // xL & uL dead from here; u2f/hnL regions become live

    // phase 4: u2f = acc2 + bias; cooperative old-h copy hb -> hnL (swizzled)
#pragma unroll
    for (int mi = 0; mi < 2; ++mi) {
#pragma unroll
        for (int ni = 0; ni < 4; ++ni) {
            const int col = wc * 64 + ni * 16 + lrow;
            const float bias = ub2[col];
#pragma unroll
            for (int r = 0; r < 4; ++r) {
                const int row = wr * 32 + mi * 16 + lgrp * 4 + r;
                u2f[row * 129 + col] = (mi == 0 ? acc2[0][ni][r] : acc2[1][ni][r]) + bias;
            }
        }
    }
    for (int i = tid; i < 64 * 16; i += 256) {
        const int row = i >> 4, cc = i & 15;
        const int node = nb0 + row;
        bf16x8 v;
        if (node < NN) v = *(const bf16x8*)(hb + (size_t)node * 128 + cc * 8);
        else { for (int j = 0; j < 8; ++j) v[j] = (bf16)0.0f; }
        *(bf16x8*)(hnL + row * 128 + ((cc ^ (row & 15)) * 8)) = v;
    }
    __syncthreads();

    // phase 5: LN tail (4 lanes/row); lig rows overwrite hnL + global h
    {
        const int row = tid >> 2, sl = tid & 3;
        const int node = nb0 + row;
        const bool lig = (node < NN) && (node_type[node] == 1);
        float sum = 0.0f, sq = 0.0f;
        if (lig) {
#pragma unroll
            for (int k = 0; k < 32; ++k) {
                const int c = sl + (k << 2);
                float s = hg[(size_t)node * 128 + c] + u2f[row * 129 + c];
                u2f[row * 129 + c] = s;
                sum += s; sq += s * s;
            }
        }
        sum += __shfl_xor(sum, 1); sq += __shfl_xor(sq, 1);
        sum += __shfl_xor(sum, 2); sq += __shfl_xor(sq, 2);
        if (lig) {
            const float mu = sum * (1.0f / 128.0f);
            const float var = sq * (1.0f / 128.0f) - mu * mu;
            const float rstd = rsqrtf(var + 1e-5f);
#pragma unroll
            for (int k = 0; k < 32; ++k) {
                const int c = sl + (k << 2);
                float s = u2f[row * 129 + c];
                float o = (s - mu) * rstd * ng[c] + nb_[c];
                hg[(size_t)node * 128 + c] = o;
                hb[(size_t)node * 128 + c] = (bf16)o;
                const int cc = c >> 3;
                hnL[row * 128 + ((cc ^ (row & 15)) << 3) + (c & 7)] = (bf16)o;
            }
        }
    }
    if (!compute_x) return;
    __syncthreads();

    // phase 6: next-layer X-GEMM: X = hnew @ [W1a | W1b]
    f32x4 accX[2][8] = {};
    for (int ks = 0; ks < 4; ++ks) {
        const int cb = ks * 4 + lgrp;
        bf16x8 a0 = *(const bf16x8*)(hnL + r0 * 128 + ((cb ^ (r0 & 15)) * 8));
        bf16x8 a1 = *(const bf16x8*)(hnL + r1 * 128 + ((cb ^ (r1 & 15)) * 8));
        const int k0 = ks * 32 + lgrp * 8;
#pragma unroll
        for (int ni = 0; ni < 8; ++ni) {
            const int col = wc * 128 + ni * 16 + lrow;
            bf16x8 b = *(const bf16x8*)(W1abt_next + (size_t)col * 128 + k0);
            accX[0][ni] = __builtin_amdgcn_mfma_f32_16x16x32_bf16(a0, b, accX[0][ni], 0, 0, 0);
            accX[1][ni] = __builtin_amdgcn_mfma_f32_16x16x32_bf16(a1, b, accX[1][ni], 0, 0, 0);
        }
    }
#pragma unroll
    for (int mi = 0; mi < 2; ++mi) {
#pragma unroll
        for (int r = 0; r < 4; ++r) {
            const int row = wr * 32 + mi * 16 + lgrp * 4 + r;
            const int node = nb0 + row;
            if (node >= NN) continue;
#pragma unroll
            for (int ni = 0; ni < 8; ++ni) {
                const int col = wc * 128 + ni * 16 + lrow;
                float v = (mi == 0 ? accX[0][ni][r] : accX[1][ni][r]);
                if (col < 128) Xsb[(size_t)node * 128 + col] = (bf16)v;
                else Xdb[(size_t)node * 128 + (col - 128)] = (bf16)v;
            }
        }
    }
}

// ---------------------------------------------------------------- pooling + head
__global__ void pool_kernel(const int* __restrict__ nt, const int* __restrict__ batch,
                            const float* __restrict__ hg, float* __restrict__ gsum,
                            float* __restrict__ gcnt) {
    int idx = blockIdx.x * 256 + threadIdx.x;
    int n = idx >> 7, c = idx & 127;
    if (n >= NN) return;
    if (nt[n] == 1) {
        int b = batch[n];
        atomicAdd(&gsum[b * 128 + c], hg[(size_t)n * 128 + c]);
        if (c == 0) atomicAdd(&gcnt[b], 1.0f);
    }
}

__global__ void head_kernel(const float* __restrict__ gsum, const float* __restrict__ gcnt,
                            const float* __restrict__ w1, const float* __restrict__ b1,
                            const float* __restrict__ w2, const float* __restrict__ b2,
                            float* __restrict__ out) {
    int g = blockIdx.x, c = threadIdx.x;  // 128 threads
    __shared__ float gfL[128], uH[128];
    float inv = 1.0f / fmaxf(gcnt[g], 1.0f);
    gfL[c] = gsum[g * 128 + c] * inv;
    __syncthreads();
    float acc = b1[c];
    for (int k = 0; k < 128; ++k) acc += gfL[k] * w1[k * 128 + c];
    uH[c] = silu_f(acc);
    __syncthreads();
    gfL[c] = uH[c] * w2[c];
    __syncthreads();
    for (int s = 64; s > 0; s >>= 1) { if (c < s) gfL[c] += gfL[c + s]; __syncthreads(); }
    if (c == 0) out[g] = gfL[0] + b2[0];
}

// ---------------------------------------------------------------- launch
extern "C" void kernel_launch(void* const* d_in, const int* in_sizes, int n_in,
                              void* d_out, int out_size, void* d_ws, size_t ws_size,
                              hipStream_t stream) {
    const int* z = (const int*)d_in[0];
    const int* node_type = (const int*)d_in[1];
    const float* pos = (const float*)d_in[2];
    const int* edge_index = (const int*)d_in[3];
    const int* edge_type = (const int*)d_in[4];
    const int* batch = (const int*)d_in[5];
    const float* t_in = (const float*)d_in[6];
    const float* emb_z = (const float*)d_in[7];
    const float* emb_nt = (const float*)d_in[8];
    const float* in_norm_g = (const float*)d_in[9];
    const float* in_norm_b = (const float*)d_in[10];
    const float* time_w1 = (const float*)d_in[11];
    const float* time_b1 = (const float*)d_in[12];
    const float* time_w2 = (const float*)d_in[13];
    const float* time_b2 = (const float*)d_in[14];
    const float* l_edge_emb = (const float*)d_in[15];
    const float* l_msg_w1 = (const float*)d_in[16];
    const float* l_msg_b1 = (const float*)d_in[17];
    const float* l_msg_w2 = (const float*)d_in[18];
    const float* l_msg_b2 = (const float*)d_in[19];
    const float* l_upd_w1 = (const float*)d_in[20];
    const float* l_upd_b1 = (const float*)d_in[21];
    const float* l_upd_w2 = (const float*)d_in[22];
    const float* l_upd_b2 = (const float*)d_in[23];
    const float* l_norm_g = (const float*)d_in[24];
    const float* l_norm_b = (const float*)d_in[25];
    const float* head_w1 = (const float*)d_in[26];
    const float* head_b1 = (const float*)d_in[27];
    const float* head_w2 = (const float*)d_in[28];
    const float* head_b2 = (const float*)d_in[29];
    float* out = (float*)d_out;

    char* w = (char*)d_ws;
    auto alloc = [&](size_t bytes) {
        char* p = w;
        w += (bytes + 255) & ~(size_t)255;
        return p;
    };
    float* hg = (float*)alloc((size_t)NN * 128 * 4);
    bf16* hb = (bf16*)alloc((size_t)NN * 128 * 2);
    float* sums = (float*)alloc((size_t)NN * 128 * 4);
    bf16* Xsb = (bf16*)alloc((size_t)NN * 128 * 2);
    bf16* Xdb = (bf16*)alloc((size_t)NN * 128 * 2);
    int* cnt = (int*)alloc((size_t)NN * 4);
    int* cursor = (int*)alloc((size_t)NN * 4);
    int* su_s = (int*)alloc((size_t)EE * 4);
    int* dst_s = (int*)alloc((size_t)EE * 4);
    float* dist_s = (float*)alloc((size_t)EE * 4);
    float* dist_raw = (float*)alloc((size_t)EE * 4);
    bf16* W1abt = (bf16*)alloc((size_t)4 * 256 * 128 * 2);
    bf16* W1rt = (bf16*)alloc((size_t)4 * 128 * 64 * 2);
    bf16* W2t = (bf16*)alloc((size_t)4 * 128 * 128 * 2);
    bf16* U1t = (bf16*)alloc((size_t)4 * 128 * 256 * 2);
    bf16* U2t = (bf16*)alloc((size_t)4 * 128 * 128 * 2);
    float* tf = (float*)alloc((size_t)GG * 128 * 4);
    float* gsum = (float*)alloc((size_t)GG * 128 * 4);
    float* gcnt = (float*)alloc((size_t)GG * 4);

    hipMemsetAsync(cnt, 0, (size_t)NN * 4, stream);
    hipMemsetAsync(sums, 0, (size_t)NN * 128 * 4, stream);  // node_kernel re-zeros per layer
    prep_weights<<<1664, 256, 0, stream>>>(l_msg_w1, l_msg_w2, l_upd_w1, l_upd_w2,
                                           l_edge_emb, l_msg_b1, W1abt, W1rt, W2t, U1t, U2t);
    time_mlp<<<GG, 128, 0, stream>>>(t_in, time_w1, time_b1, time_w2, time_b2, tf);
    edge_pre<<<(EE + 255) / 256, 256, 0, stream>>>(edge_index, pos, dist_raw, cnt);
    scan_kernel<<<1, 1024, 0, stream>>>(cnt, cursor);
    scatter_kernel<<<(EE + 255) / 256, 256, 0, stream>>>(edge_index, edge_type, dist_raw,
                                                         cursor, su_s, dst_s, dist_s);
    node_init_fused<<<(NN + 63) / 64, 256, 0, stream>>>(
        z, node_type, batch, tf, emb_z, emb_nt, in_norm_g, in_norm_b,
        hg, hb, W1abt, Xsb, Xdb);
    for (int l = 0; l < 4; ++l) {
        edge_kernel<<<EE / 64, 256, 0, stream>>>(
            su_s, dst_s, dist_s, Xsb, Xdb, W1rt + (size_t)l * 8192,
            W2t + (size_t)l * 16384, l_msg_b2 + l * 128, sums);
        const int nl = (l < 3) ? (l + 1) : 0;
        node_kernel<<<(NN + 63) / 64, 256, 0, stream>>>(
            hg, hb, sums, cnt, node_type, U1t + (size_t)l * 32768, U2t + (size_t)l * 16384,
            l_upd_b1 + l * 128, l_upd_b2 + l * 128, l_norm_g + l * 128, l_norm_b + l * 128,
            W1abt + (size_t)nl * 32768, Xsb, Xdb, (l < 3) ? 1 : 0);
    }
    hipMemsetAsync(gsum, 0, (size_t)GG * 128 * 4, stream);
    hipMemsetAsync(gcnt, 0, (size_t)GG * 4, stream);
    pool_kernel<<<(NN * 128 + 255) / 256, 256, 0, stream>>>(node_type, batch, hg, gsum, gcnt);
    head_kernel<<<GG, 128, 0, stream>>>(gsum, gcnt, head_w1, head_b1, head_w2, head_b2, out);
}